// Round 1
// baseline (462.625 us; speedup 1.0000x reference)
//
#include <hip/hip_runtime.h>
#include <math.h>

#define BN_EPS 1e-5f

// ---------------- CSR build ----------------

__global__ void k_zero2(int* __restrict__ a, int* __restrict__ b, int n) {
  int i = blockIdx.x * blockDim.x + threadIdx.x;
  if (i < n) { a[i] = 0; b[i] = 0; }
}

__global__ void k_count(const int* __restrict__ dst, int* __restrict__ deg, int E) {
  int e = blockIdx.x * blockDim.x + threadIdx.x;
  if (e < E) atomicAdd(&deg[dst[e]], 1);
}

__global__ void k_scan1(const int* __restrict__ deg, int* __restrict__ rowstart,
                        int* __restrict__ chunksum, int n) {
  __shared__ int s[1024];
  int i = blockIdx.x * 1024 + threadIdx.x;
  int v = (i < n) ? deg[i] : 0;
  s[threadIdx.x] = v;
  __syncthreads();
  for (int off = 1; off < 1024; off <<= 1) {
    int t = (threadIdx.x >= off) ? s[threadIdx.x - off] : 0;
    __syncthreads();
    s[threadIdx.x] += t;
    __syncthreads();
  }
  if (i < n) rowstart[i] = s[threadIdx.x] - v;   // exclusive within chunk
  if (threadIdx.x == 1023) chunksum[blockIdx.x] = s[1023];
}

__global__ void k_scan2(int* __restrict__ chunksum, int nchunks) {
  if (threadIdx.x == 0 && blockIdx.x == 0) {
    int run = 0;
    for (int i = 0; i < nchunks; i++) { int v = chunksum[i]; chunksum[i] = run; run += v; }
  }
}

__global__ void k_scan3(int* __restrict__ rowstart, const int* __restrict__ chunksum,
                        const int* __restrict__ deg, float* __restrict__ dis,
                        float* __restrict__ dinv, int n, int E) {
  int i = blockIdx.x * blockDim.x + threadIdx.x;
  if (i < n) {
    rowstart[i] += chunksum[i >> 10];
    float fd = (float)(deg[i] + 1);   // +1 self loop
    dis[i]  = rsqrtf(fd);
    dinv[i] = 1.0f / fd;
  }
  if (i == 0) rowstart[n] = E;
}

__global__ void k_fill(const int* __restrict__ ei, const int* __restrict__ rowstart,
                       int* __restrict__ cursor, const float* __restrict__ dis,
                       int* __restrict__ slot_src, float* __restrict__ slot_norm, int E) {
  int e = blockIdx.x * blockDim.x + threadIdx.x;
  if (e >= E) return;
  int s = ei[e];        // row 0 = src
  int d = ei[E + e];    // row 1 = dst
  int pos = rowstart[d] + atomicAdd(&cursor[d], 1);
  slot_src[pos]  = s;
  slot_norm[pos] = dis[s] * dis[d];
}

// ---------------- BN fold ----------------

__global__ void k_bnprep(const float* __restrict__ g1, const float* __restrict__ be1,
                         const float* __restrict__ m1, const float* __restrict__ v1,
                         const float* __restrict__ g2, const float* __restrict__ be2,
                         const float* __restrict__ m2, const float* __restrict__ v2,
                         float* __restrict__ sc1, float* __restrict__ sh1,
                         float* __restrict__ sc2, float* __restrict__ sh2) {
  int i = threadIdx.x;  // 128
  float s1 = g1[i] * rsqrtf(v1[i] + BN_EPS);
  sc1[i] = s1; sh1[i] = be1[i] - m1[i] * s1;
  float s2 = g2[i] * rsqrtf(v2[i] + BN_EPS);
  sc2[i] = s2; sh2[i] = be2[i] - m2[i] * s2;
}

// ---------------- GEMM: C[nrows x NC] = A[nrows x 128] * W[128 x NC] ----------------
// BN = LDS col tile (128 or 64, zero-padded past NC). BM = 8*1024/BN.
// 48KB LDS, 256 threads, each thread 8 rows x 4 cols.

template <int BN>
__global__ __launch_bounds__(256) void k_gemm(const float* __restrict__ A,
                                              const float* __restrict__ W,
                                              float* __restrict__ C,
                                              int nrows, int NC) {
  constexpr int BM = 8 * 1024 / BN;  // 64 (BN=128) or 128 (BN=64)
  constexpr int CG = BN / 4;
  __shared__ float As[BM][64];
  __shared__ float Ws[64][BN];
  const int tid  = threadIdx.x;
  const int row0 = blockIdx.x * BM;
  const int tc = tid % CG;       // col group (4 cols)
  const int tr = tid / CG;       // row group (8 rows)
  float acc[8][4] = {};

  for (int k0 = 0; k0 < 128; k0 += 64) {
    __syncthreads();  // protect LDS from previous compute
    // stage W tile (64 x BN), zero-pad cols >= NC
    for (int i = tid; i < 16 * BN; i += 256) {
      int r = i / CG, c4 = i % CG;
      float4 v;
      if (4 * c4 + 3 < NC) {
        v = *(const float4*)(W + (k0 + r) * NC + 4 * c4);
      } else {
        float t[4];
        for (int j = 0; j < 4; j++) { int c = 4 * c4 + j; t[j] = (c < NC) ? W[(k0 + r) * NC + c] : 0.f; }
        v = make_float4(t[0], t[1], t[2], t[3]);
      }
      *(float4*)(&Ws[r][4 * c4]) = v;
    }
    // stage A tile (BM x 64)
    for (int i = tid; i < BM * 16; i += 256) {
      int r = i / 16, c4 = i % 16;
      int gr = row0 + r;
      float4 v = make_float4(0.f, 0.f, 0.f, 0.f);
      if (gr < nrows) v = *(const float4*)(A + gr * 128 + k0 + 4 * c4);
      *(float4*)(&As[r][4 * c4]) = v;
    }
    __syncthreads();

    for (int kk = 0; kk < 64; kk += 4) {
      float4 w[4];
#pragma unroll
      for (int j = 0; j < 4; j++) w[j] = *(const float4*)(&Ws[kk + j][4 * tc]);
#pragma unroll
      for (int i = 0; i < 8; i++) {
        float4 a = *(const float4*)(&As[tr * 8 + i][kk]);
        acc[i][0] += a.x * w[0].x + a.y * w[1].x + a.z * w[2].x + a.w * w[3].x;
        acc[i][1] += a.x * w[0].y + a.y * w[1].y + a.z * w[2].y + a.w * w[3].y;
        acc[i][2] += a.x * w[0].z + a.y * w[1].z + a.z * w[2].z + a.w * w[3].z;
        acc[i][3] += a.x * w[0].w + a.y * w[1].w + a.z * w[2].w + a.w * w[3].w;
      }
    }
  }

#pragma unroll
  for (int i = 0; i < 8; i++) {
    int gr = row0 + tr * 8 + i;
    if (gr >= nrows) continue;
    int c = 4 * tc;
    if (c + 3 < NC) {
      *(float4*)(C + gr * NC + c) = make_float4(acc[i][0], acc[i][1], acc[i][2], acc[i][3]);
    } else {
      for (int j = 0; j < 4; j++) if (c + j < NC) C[gr * NC + c + j] = acc[i][j];
    }
  }
}

// ---------------- Aggregation (D=128): out = A_hat*h + b, then optional BN+ReLU ----------
// One warp (64 lanes) per node; lane handles channels {2*lane, 2*lane+1}.

__global__ __launch_bounds__(256) void k_agg128(const float* __restrict__ h,
                         const int* __restrict__ rowstart,
                         const int* __restrict__ slot_src,
                         const float* __restrict__ slot_norm,
                         const float* __restrict__ dinv,
                         const float* __restrict__ bias,
                         const float* __restrict__ bnsc,
                         const float* __restrict__ bnsh,
                         float* __restrict__ out, int nnodes) {
  int node = blockIdx.x * 4 + threadIdx.y;
  if (node >= nnodes) return;
  int c0 = threadIdx.x * 2;
  int s = rowstart[node], e = rowstart[node + 1];
  float ax = 0.f, ay = 0.f;
  for (int i = s; i < e; i++) {
    int src = slot_src[i];
    float nrm = slot_norm[i];
    float2 hv = *(const float2*)(h + src * 128 + c0);
    ax += hv.x * nrm; ay += hv.y * nrm;
  }
  float di = dinv[node];
  float2 hv = *(const float2*)(h + node * 128 + c0);
  ax += hv.x * di; ay += hv.y * di;
  float2 bb = *(const float2*)(bias + c0);
  float o0 = ax + bb.x, o1 = ay + bb.y;
  float2 sc = *(const float2*)(bnsc + c0);
  float2 sh = *(const float2*)(bnsh + c0);
  o0 = fmaxf(o0 * sc.x + sh.x, 0.f);
  o1 = fmaxf(o1 * sc.y + sh.y, 0.f);
  *(float2*)(out + node * 128 + c0) = make_float2(o0, o1);
}

// ---------------- Aggregation (D=40) + log_softmax ----------------
// One warp per node; lanes 0..39 hold channels.

__global__ __launch_bounds__(256) void k_agg40_lsm(const float* __restrict__ h,
                            const int* __restrict__ rowstart,
                            const int* __restrict__ slot_src,
                            const float* __restrict__ slot_norm,
                            const float* __restrict__ dinv,
                            const float* __restrict__ bias,
                            float* __restrict__ out, int nnodes, int NC) {
  int node = blockIdx.x * 4 + threadIdx.y;
  if (node >= nnodes) return;
  int lane = threadIdx.x;
  bool act = lane < NC;
  int s = rowstart[node], e = rowstart[node + 1];
  float acc = 0.f;
  for (int i = s; i < e; i++) {
    int src = slot_src[i];
    float nrm = slot_norm[i];
    if (act) acc += h[src * NC + lane] * nrm;
  }
  if (act) acc += h[node * NC + lane] * dinv[node] + bias[lane];
  // log_softmax over NC lanes
  float v = act ? acc : -INFINITY;
#pragma unroll
  for (int off = 32; off; off >>= 1) v = fmaxf(v, __shfl_xor(v, off));
  float ex = act ? expf(acc - v) : 0.f;
  float ss = ex;
#pragma unroll
  for (int off = 32; off; off >>= 1) ss += __shfl_xor(ss, off);
  float lse = v + logf(ss);
  if (act) out[node * NC + lane] = acc - lse;
}

// ---------------- launch ----------------

extern "C" void kernel_launch(void* const* d_in, const int* in_sizes, int n_in,
                              void* d_out, int out_size, void* d_ws, size_t ws_size,
                              hipStream_t stream) {
  const float* x   = (const float*)d_in[0];
  const int*   ei  = (const int*)d_in[1];
  const float* W1  = (const float*)d_in[2];
  const float* b1  = (const float*)d_in[3];
  const float* W2  = (const float*)d_in[4];
  const float* b2  = (const float*)d_in[5];
  const float* W3  = (const float*)d_in[6];
  const float* b3  = (const float*)d_in[7];
  const float* g1  = (const float*)d_in[8];
  const float* be1 = (const float*)d_in[9];
  const float* m1  = (const float*)d_in[10];
  const float* v1  = (const float*)d_in[11];
  const float* g2  = (const float*)d_in[12];
  const float* be2 = (const float*)d_in[13];
  const float* m2  = (const float*)d_in[14];
  const float* v2  = (const float*)d_in[15];

  const int N  = in_sizes[0] / 128;
  const int E  = in_sizes[1] / 2;
  const int NC3 = in_sizes[6] / 128;   // 40

  float* outp = (float*)d_out;

  // workspace carve-up (256B aligned)
  char* ws = (char*)d_ws;
  size_t off = 0;
  auto alloc = [&](size_t bytes) -> char* {
    char* p = ws + off;
    off = (off + bytes + 255) & ~(size_t)255;
    return p;
  };
  int*   deg       = (int*)alloc((size_t)N * 4);
  int*   cursor    = (int*)alloc((size_t)N * 4);
  int*   rowstart  = (int*)alloc((size_t)(N + 1) * 4);
  int*   chunksum  = (int*)alloc(256 * 4);
  float* dis       = (float*)alloc((size_t)N * 4);
  float* dinv      = (float*)alloc((size_t)N * 4);
  int*   slot_src  = (int*)alloc((size_t)E * 4);
  float* slot_norm = (float*)alloc((size_t)E * 4);
  float* sc1       = (float*)alloc(128 * 4);
  float* sh1       = (float*)alloc(128 * 4);
  float* sc2       = (float*)alloc(128 * 4);
  float* sh2       = (float*)alloc(128 * 4);
  float* bufA      = (float*)alloc((size_t)N * 128 * 4);
  float* bufB      = (float*)alloc((size_t)N * 128 * 4);
  (void)ws_size;

  const int T = 256;
  const int chunks = (N + 1023) / 1024;

  // CSR build
  k_zero2<<<(N + T - 1) / T, T, 0, stream>>>(deg, cursor, N);
  k_count<<<(E + T - 1) / T, T, 0, stream>>>(ei + E, deg, E);
  k_scan1<<<chunks, 1024, 0, stream>>>(deg, rowstart, chunksum, N);
  k_scan2<<<1, 64, 0, stream>>>(chunksum, chunks);
  k_scan3<<<(N + T - 1) / T, T, 0, stream>>>(rowstart, chunksum, deg, dis, dinv, N, E);
  k_fill<<<(E + T - 1) / T, T, 0, stream>>>(ei, rowstart, cursor, dis, slot_src, slot_norm, E);
  k_bnprep<<<1, 128, 0, stream>>>(g1, be1, m1, v1, g2, be2, m2, v2, sc1, sh1, sc2, sh2);

  dim3 aggGrid((N + 3) / 4), aggBlk(64, 4);

  // Layer 1: tmp = x@W1 ; A = relu(bn(agg(tmp)+b1))
  k_gemm<128><<<(N + 63) / 64, 256, 0, stream>>>(x, W1, bufB, N, 128);
  k_agg128<<<aggGrid, aggBlk, 0, stream>>>(bufB, rowstart, slot_src, slot_norm, dinv, b1, sc1, sh1, bufA, N);

  // Layer 2
  k_gemm<128><<<(N + 63) / 64, 256, 0, stream>>>(bufA, W2, bufB, N, 128);
  k_agg128<<<aggGrid, aggBlk, 0, stream>>>(bufB, rowstart, slot_src, slot_norm, dinv, b2, sc2, sh2, bufA, N);

  // Layer 3 + log_softmax
  k_gemm<64><<<(N + 127) / 128, 256, 0, stream>>>(bufA, W3, bufB, N, NC3);
  k_agg40_lsm<<<aggGrid, aggBlk, 0, stream>>>(bufB, rowstart, slot_src, slot_norm, dinv, b3, outp, N, NC3);
}

// Round 2
// 386.267 us; speedup vs baseline: 1.1977x; 1.1977x over previous
//
#include <hip/hip_runtime.h>
#include <math.h>

#define BN_EPS 1e-5f

typedef __attribute__((ext_vector_type(8))) short bf16x8;
typedef __attribute__((ext_vector_type(4))) float f32x4;

__device__ inline ushort f2bf(float f) {
  union { float f; unsigned u; } v; v.f = f;
  unsigned r = v.u + 0x7FFF + ((v.u >> 16) & 1);   // round-nearest-even
  return (ushort)(r >> 16);
}

// ---------------- CSR build ----------------

__global__ void k_zero2(int* __restrict__ a, int* __restrict__ b, int n) {
  int i = blockIdx.x * blockDim.x + threadIdx.x;
  if (i < n) { a[i] = 0; b[i] = 0; }
}

__global__ void k_count(const int* __restrict__ dst, int* __restrict__ deg, int E) {
  int e = blockIdx.x * blockDim.x + threadIdx.x;
  if (e < E) atomicAdd(&deg[dst[e]], 1);
}

__global__ void k_scan1(const int* __restrict__ deg, int* __restrict__ rowstart,
                        int* __restrict__ chunksum, int n) {
  __shared__ int s[1024];
  int i = blockIdx.x * 1024 + threadIdx.x;
  int v = (i < n) ? deg[i] : 0;
  s[threadIdx.x] = v;
  __syncthreads();
  for (int off = 1; off < 1024; off <<= 1) {
    int t = (threadIdx.x >= off) ? s[threadIdx.x - off] : 0;
    __syncthreads();
    s[threadIdx.x] += t;
    __syncthreads();
  }
  if (i < n) rowstart[i] = s[threadIdx.x] - v;   // exclusive within chunk
  if (threadIdx.x == 1023) chunksum[blockIdx.x] = s[1023];
}

__global__ void k_scan2(int* __restrict__ chunksum, int nchunks) {
  if (threadIdx.x == 0 && blockIdx.x == 0) {
    int run = 0;
    for (int i = 0; i < nchunks; i++) { int v = chunksum[i]; chunksum[i] = run; run += v; }
  }
}

__global__ void k_scan3(int* __restrict__ rowstart, const int* __restrict__ chunksum,
                        const int* __restrict__ deg, float* __restrict__ dis,
                        float* __restrict__ dinv, int n, int E) {
  int i = blockIdx.x * blockDim.x + threadIdx.x;
  if (i < n) {
    rowstart[i] += chunksum[i >> 10];
    float fd = (float)(deg[i] + 1);   // +1 self loop
    dis[i]  = rsqrtf(fd);
    dinv[i] = 1.0f / fd;
  }
  if (i == 0) rowstart[n] = E;
}

__global__ void k_fill(const int* __restrict__ ei, const int* __restrict__ rowstart,
                       int* __restrict__ cursor, const float* __restrict__ dis,
                       int2* __restrict__ slot, int E) {
  int e = blockIdx.x * blockDim.x + threadIdx.x;
  if (e >= E) return;
  int s = ei[e];        // row 0 = src
  int d = ei[E + e];    // row 1 = dst
  int pos = rowstart[d] + atomicAdd(&cursor[d], 1);
  int2 p; p.x = s; p.y = __float_as_int(dis[s] * dis[d]);
  slot[pos] = p;
}

// ---------------- small prep: BN fold, weight transpose+bf16, x -> bf16 ----------------

__global__ void k_bnprep(const float* __restrict__ g1, const float* __restrict__ be1,
                         const float* __restrict__ m1, const float* __restrict__ v1,
                         const float* __restrict__ g2, const float* __restrict__ be2,
                         const float* __restrict__ m2, const float* __restrict__ v2,
                         float* __restrict__ sc1, float* __restrict__ sh1,
                         float* __restrict__ sc2, float* __restrict__ sh2) {
  int i = threadIdx.x;  // 128
  float s1 = g1[i] * rsqrtf(v1[i] + BN_EPS);
  sc1[i] = s1; sh1[i] = be1[i] - m1[i] * s1;
  float s2 = g2[i] * rsqrtf(v2[i] + BN_EPS);
  sc2[i] = s2; sh2[i] = be2[i] - m2[i] * s2;
}

// WT[n][k] = W[k][n], bf16, n padded to 128 with zeros for W3
__global__ void k_prep_w(const float* __restrict__ W1, const float* __restrict__ W2,
                         const float* __restrict__ W3,
                         ushort* __restrict__ WT1, ushort* __restrict__ WT2,
                         ushort* __restrict__ WT3) {
  int k = blockIdx.x;      // 128
  int n = threadIdx.x;     // 128
  WT1[n * 128 + k] = f2bf(W1[k * 128 + n]);
  WT2[n * 128 + k] = f2bf(W2[k * 128 + n]);
  WT3[n * 128 + k] = (n < 40) ? f2bf(W3[k * 40 + n]) : (ushort)0;
}

__global__ void k_cvt(const float* __restrict__ in, ushort* __restrict__ out, int n4) {
  int i = blockIdx.x * blockDim.x + threadIdx.x;
  if (i >= n4) return;
  float4 v = *(const float4*)(in + (size_t)i * 4);
  ushort4 o; o.x = f2bf(v.x); o.y = f2bf(v.y); o.z = f2bf(v.z); o.w = f2bf(v.w);
  *(ushort4*)(out + (size_t)i * 4) = o;
}

// ---------------- MFMA GEMM: C[nrows x NC](bf16) = A[nrows x 128](bf16) * W[128 x NC] ----
// WT is the 128x128 (n-major, k-contiguous) bf16 pre-transposed weight, zero-padded cols.
// 128x128 block tile, 4 waves in 2x2 grid, each wave 64x64 via 4x4 frags of 16x16x32.

__global__ __launch_bounds__(256) void k_gemm_bf16(const ushort* __restrict__ A,
                                                   const ushort* __restrict__ WT,
                                                   ushort* __restrict__ C,
                                                   int nrows, int NC) {
  __shared__ ushort As[128][80];   // +16B pad: staging writes 2-way, frag reads 4-way
  __shared__ ushort Bs[128][80];
  const int tid  = threadIdx.x;
  const int lane = tid & 63;
  const int wid  = tid >> 6;
  const int wr   = wid >> 1, wc = wid & 1;
  const int row0 = blockIdx.x * 128;
  f32x4 acc[4][4] = {};

  const int mrow = lane & 15;
  const int kg   = (lane >> 4) * 8;

  for (int k0 = 0; k0 < 128; k0 += 64) {
    __syncthreads();
    for (int i = tid; i < 1024; i += 256) {        // A tile: 128 rows x 64 bf16
      int r = i >> 3, c = (i & 7) * 8;
      uint4 v = make_uint4(0, 0, 0, 0);
      if (row0 + r < nrows) v = *(const uint4*)(A + (size_t)(row0 + r) * 128 + k0 + c);
      *(uint4*)(&As[r][c]) = v;
    }
    for (int i = tid; i < 1024; i += 256) {        // B tile: 128 n-rows x 64 bf16 (k)
      int r = i >> 3, c = (i & 7) * 8;
      *(uint4*)(&Bs[r][c]) = *(const uint4*)(WT + r * 128 + k0 + c);
    }
    __syncthreads();

#pragma unroll
    for (int ks = 0; ks < 2; ks++) {
      bf16x8 a[4], b[4];
#pragma unroll
      for (int f = 0; f < 4; f++) {
        a[f] = *(const bf16x8*)(&As[wr * 64 + f * 16 + mrow][ks * 32 + kg]);
        b[f] = *(const bf16x8*)(&Bs[wc * 64 + f * 16 + mrow][ks * 32 + kg]);
      }
#pragma unroll
      for (int fm = 0; fm < 4; fm++)
#pragma unroll
        for (int fn = 0; fn < 4; fn++)
          acc[fm][fn] = __builtin_amdgcn_mfma_f32_16x16x32_bf16(a[fm], b[fn], acc[fm][fn], 0, 0, 0);
    }
  }

  // C/D layout: col = lane&15, row = (lane>>4)*4 + reg
  const int rl = (lane >> 4) * 4;
  const int cl = lane & 15;
#pragma unroll
  for (int fm = 0; fm < 4; fm++) {
#pragma unroll
    for (int r = 0; r < 4; r++) {
      int row = row0 + wr * 64 + fm * 16 + rl + r;
      if (row >= nrows) continue;
#pragma unroll
      for (int fn = 0; fn < 4; fn++) {
        int col = wc * 64 + fn * 16 + cl;
        if (col < NC) C[(size_t)row * NC + col] = f2bf(acc[fm][fn][r]);
      }
    }
  }
}

// ---------------- Aggregation (D=128, bf16 in/out): out = relu(bn(A_hat*h + b)) --------
// One wave per node; lane handles channels {2*lane, 2*lane+1} (one 4B load per edge).

__global__ __launch_bounds__(256) void k_agg128b(const ushort* __restrict__ h,
                          const int* __restrict__ rowstart,
                          const int2* __restrict__ slot,
                          const float* __restrict__ dinv,
                          const float* __restrict__ bias,
                          const float* __restrict__ bnsc,
                          const float* __restrict__ bnsh,
                          ushort* __restrict__ out, int nnodes) {
  int node = blockIdx.x * 4 + threadIdx.y;
  if (node >= nnodes) return;
  int lane = threadIdx.x;
  int c0 = lane * 2;
  int s = rowstart[node], e = rowstart[node + 1];
  float ax = 0.f, ay = 0.f;
  for (int i = s; i < e; i++) {
    int2 p = slot[i];
    float nrm = __int_as_float(p.y);
    unsigned hv = *(const unsigned*)(h + (size_t)p.x * 128 + c0);
    ax += __uint_as_float(hv << 16) * nrm;
    ay += __uint_as_float(hv & 0xffff0000u) * nrm;
  }
  float di = dinv[node];
  unsigned hv = *(const unsigned*)(h + (size_t)node * 128 + c0);
  ax += __uint_as_float(hv << 16) * di;
  ay += __uint_as_float(hv & 0xffff0000u) * di;
  float2 bb = *(const float2*)(bias + c0);
  float2 sc = *(const float2*)(bnsc + c0);
  float2 sh = *(const float2*)(bnsh + c0);
  float o0 = fmaxf((ax + bb.x) * sc.x + sh.x, 0.f);
  float o1 = fmaxf((ay + bb.y) * sc.y + sh.y, 0.f);
  *(unsigned*)(out + (size_t)node * 128 + c0) = (unsigned)f2bf(o0) | ((unsigned)f2bf(o1) << 16);
}

// ---------------- Aggregation (D=40, bf16 in) + log_softmax (fp32 out) -----------------

__global__ __launch_bounds__(256) void k_agg40_lsm(const ushort* __restrict__ h,
                            const int* __restrict__ rowstart,
                            const int2* __restrict__ slot,
                            const float* __restrict__ dinv,
                            const float* __restrict__ bias,
                            float* __restrict__ out, int nnodes, int NC) {
  int node = blockIdx.x * 4 + threadIdx.y;
  if (node >= nnodes) return;
  int lane = threadIdx.x;
  bool act = lane < NC;
  int s = rowstart[node], e = rowstart[node + 1];
  float acc = 0.f;
  for (int i = s; i < e; i++) {
    int2 p = slot[i];
    float nrm = __int_as_float(p.y);
    if (act) acc += __uint_as_float((unsigned)h[(size_t)p.x * NC + lane] << 16) * nrm;
  }
  if (act) acc += __uint_as_float((unsigned)h[(size_t)node * NC + lane] << 16) * dinv[node] + bias[lane];
  float v = act ? acc : -INFINITY;
#pragma unroll
  for (int off = 32; off; off >>= 1) v = fmaxf(v, __shfl_xor(v, off));
  float ex = act ? expf(acc - v) : 0.f;
  float ss = ex;
#pragma unroll
  for (int off = 32; off; off >>= 1) ss += __shfl_xor(ss, off);
  float lse = v + logf(ss);
  if (act) out[(size_t)node * NC + lane] = acc - lse;
}

// ---------------- launch ----------------

extern "C" void kernel_launch(void* const* d_in, const int* in_sizes, int n_in,
                              void* d_out, int out_size, void* d_ws, size_t ws_size,
                              hipStream_t stream) {
  const float* x   = (const float*)d_in[0];
  const int*   ei  = (const int*)d_in[1];
  const float* W1  = (const float*)d_in[2];
  const float* b1  = (const float*)d_in[3];
  const float* W2  = (const float*)d_in[4];
  const float* b2  = (const float*)d_in[5];
  const float* W3  = (const float*)d_in[6];
  const float* b3  = (const float*)d_in[7];
  const float* g1  = (const float*)d_in[8];
  const float* be1 = (const float*)d_in[9];
  const float* m1  = (const float*)d_in[10];
  const float* v1  = (const float*)d_in[11];
  const float* g2  = (const float*)d_in[12];
  const float* be2 = (const float*)d_in[13];
  const float* m2  = (const float*)d_in[14];
  const float* v2  = (const float*)d_in[15];

  const int N   = in_sizes[0] / 128;
  const int E   = in_sizes[1] / 2;
  const int NC3 = in_sizes[6] / 128;   // 40

  float* outp = (float*)d_out;

  char* ws = (char*)d_ws;
  size_t off = 0;
  auto alloc = [&](size_t bytes) -> char* {
    char* p = ws + off;
    off = (off + bytes + 255) & ~(size_t)255;
    return p;
  };
  int*    deg      = (int*)alloc((size_t)N * 4);
  int*    cursor   = (int*)alloc((size_t)N * 4);
  int*    rowstart = (int*)alloc((size_t)(N + 1) * 4);
  int*    chunksum = (int*)alloc(256 * 4);
  float*  dis      = (float*)alloc((size_t)N * 4);
  float*  dinv     = (float*)alloc((size_t)N * 4);
  int2*   slot     = (int2*)alloc((size_t)E * 8);
  float*  sc1      = (float*)alloc(128 * 4);
  float*  sh1      = (float*)alloc(128 * 4);
  float*  sc2      = (float*)alloc(128 * 4);
  float*  sh2      = (float*)alloc(128 * 4);
  ushort* WT1      = (ushort*)alloc(128 * 128 * 2);
  ushort* WT2      = (ushort*)alloc(128 * 128 * 2);
  ushort* WT3      = (ushort*)alloc(128 * 128 * 2);
  ushort* xb       = (ushort*)alloc((size_t)N * 128 * 2);
  ushort* bufA     = (ushort*)alloc((size_t)N * 128 * 2);
  ushort* bufB     = (ushort*)alloc((size_t)N * 128 * 2);
  ushort* bufC     = (ushort*)alloc((size_t)N * 40 * 2);
  (void)ws_size;

  const int T = 256;
  const int chunks = (N + 1023) / 1024;

  // CSR build + prep
  k_zero2<<<(N + T - 1) / T, T, 0, stream>>>(deg, cursor, N);
  k_count<<<(E + T - 1) / T, T, 0, stream>>>(ei + E, deg, E);
  k_scan1<<<chunks, 1024, 0, stream>>>(deg, rowstart, chunksum, N);
  k_scan2<<<1, 64, 0, stream>>>(chunksum, chunks);
  k_scan3<<<(N + T - 1) / T, T, 0, stream>>>(rowstart, chunksum, deg, dis, dinv, N, E);
  k_fill<<<(E + T - 1) / T, T, 0, stream>>>(ei, rowstart, cursor, dis, slot, E);
  k_bnprep<<<1, 128, 0, stream>>>(g1, be1, m1, v1, g2, be2, m2, v2, sc1, sh1, sc2, sh2);
  k_prep_w<<<128, 128, 0, stream>>>(W1, W2, W3, WT1, WT2, WT3);
  k_cvt<<<(N * 128 / 4 + T - 1) / T, T, 0, stream>>>(x, xb, N * 128 / 4);

  dim3 aggGrid((N + 3) / 4), aggBlk(64, 4);
  const int gBlocks = (N + 127) / 128;

  // Layer 1
  k_gemm_bf16<<<gBlocks, 256, 0, stream>>>(xb, WT1, bufB, N, 128);
  k_agg128b<<<aggGrid, aggBlk, 0, stream>>>(bufB, rowstart, slot, dinv, b1, sc1, sh1, bufA, N);

  // Layer 2
  k_gemm_bf16<<<gBlocks, 256, 0, stream>>>(bufA, WT2, bufB, N, 128);
  k_agg128b<<<aggGrid, aggBlk, 0, stream>>>(bufB, rowstart, slot, dinv, b2, sc2, sh2, bufA, N);

  // Layer 3 + log_softmax
  k_gemm_bf16<<<gBlocks, 256, 0, stream>>>(bufA, WT3, bufC, N, NC3);
  k_agg40_lsm<<<aggGrid, aggBlk, 0, stream>>>(bufC, rowstart, slot, dinv, b3, outp, N, NC3);
}

// Round 3
// 235.210 us; speedup vs baseline: 1.9669x; 1.6422x over previous
//
#include <hip/hip_runtime.h>
#include <math.h>

#define BN_EPS 1e-5f

typedef __attribute__((ext_vector_type(8))) short bf16x8;
typedef __attribute__((ext_vector_type(4))) float f32x4;

__device__ inline unsigned f2bf(float f) {
  union { float f; unsigned u; } v; v.f = f;
  unsigned r = v.u + 0x7FFF + ((v.u >> 16) & 1);   // round-nearest-even
  return r >> 16;
}

__device__ inline void acc8(float* a, uint4 v, float nrm) {
  a[0] += __uint_as_float(v.x << 16) * nrm;
  a[1] += __uint_as_float(v.x & 0xffff0000u) * nrm;
  a[2] += __uint_as_float(v.y << 16) * nrm;
  a[3] += __uint_as_float(v.y & 0xffff0000u) * nrm;
  a[4] += __uint_as_float(v.z << 16) * nrm;
  a[5] += __uint_as_float(v.z & 0xffff0000u) * nrm;
  a[6] += __uint_as_float(v.w << 16) * nrm;
  a[7] += __uint_as_float(v.w & 0xffff0000u) * nrm;
}

__device__ inline void acc4(float* a, uint2 v, float nrm) {
  a[0] += __uint_as_float(v.x << 16) * nrm;
  a[1] += __uint_as_float(v.x & 0xffff0000u) * nrm;
  a[2] += __uint_as_float(v.y << 16) * nrm;
  a[3] += __uint_as_float(v.y & 0xffff0000u) * nrm;
}

// ---------------- CSR build ----------------

__global__ void k_count(const int* __restrict__ dst, int* __restrict__ deg, int E) {
  int e = blockIdx.x * blockDim.x + threadIdx.x;
  if (e < E) atomicAdd(&deg[dst[e]], 1);
}

__global__ void k_scan1(const int* __restrict__ deg, int* __restrict__ rowstart,
                        int* __restrict__ chunksum, int n) {
  __shared__ int s[1024];
  int i = blockIdx.x * 1024 + threadIdx.x;
  int v = (i < n) ? deg[i] : 0;
  s[threadIdx.x] = v;
  __syncthreads();
  for (int off = 1; off < 1024; off <<= 1) {
    int t = (threadIdx.x >= off) ? s[threadIdx.x - off] : 0;
    __syncthreads();
    s[threadIdx.x] += t;
    __syncthreads();
  }
  if (i < n) rowstart[i] = s[threadIdx.x] - v;   // exclusive within chunk
  if (threadIdx.x == 1023) chunksum[blockIdx.x] = s[1023];
}

__global__ void k_scan2(int* __restrict__ chunksum, int nchunks) {
  if (threadIdx.x == 0 && blockIdx.x == 0) {
    int run = 0;
    for (int i = 0; i < nchunks; i++) { int v = chunksum[i]; chunksum[i] = run; run += v; }
  }
}

__global__ void k_scan3(int* __restrict__ rowstart, const int* __restrict__ chunksum,
                        const int* __restrict__ deg, float* __restrict__ dis,
                        float* __restrict__ dinv, int n, int E) {
  int i = blockIdx.x * blockDim.x + threadIdx.x;
  if (i < n) {
    rowstart[i] += chunksum[i >> 10];
    float fd = (float)(deg[i] + 1);   // +1 self loop
    dis[i]  = rsqrtf(fd);
    dinv[i] = 1.0f / fd;
  }
  if (i == 0) rowstart[n] = E;
}

__global__ void k_fill(const int* __restrict__ ei, const int* __restrict__ rowstart,
                       int* __restrict__ cursor, const float* __restrict__ dis,
                       int2* __restrict__ slot, int E) {
  int e = blockIdx.x * blockDim.x + threadIdx.x;
  if (e >= E) return;
  int s = ei[e];        // row 0 = src
  int d = ei[E + e];    // row 1 = dst
  int pos = rowstart[d] + atomicAdd(&cursor[d], 1);
  int2 p; p.x = s; p.y = __float_as_int(dis[s] * dis[d]);
  slot[pos] = p;
}

// ------------- prep: BN fold + weight transpose/bf16 + b3 pad (one kernel) -------------
// grid 128 blocks x 128 threads; block k handles W row k; block 0/1 also do scalars.

__global__ void k_prep(const float* __restrict__ W1, const float* __restrict__ W2,
                       const float* __restrict__ W3,
                       const float* __restrict__ g1, const float* __restrict__ be1,
                       const float* __restrict__ m1, const float* __restrict__ v1,
                       const float* __restrict__ g2, const float* __restrict__ be2,
                       const float* __restrict__ m2, const float* __restrict__ v2,
                       const float* __restrict__ b3,
                       ushort* __restrict__ WT1, ushort* __restrict__ WT2,
                       ushort* __restrict__ WT3,
                       float* __restrict__ sc1, float* __restrict__ sh1,
                       float* __restrict__ sc2, float* __restrict__ sh2,
                       float* __restrict__ b3pad) {
  int k = blockIdx.x;      // 128
  int n = threadIdx.x;     // 128
  WT1[n * 128 + k] = (ushort)f2bf(W1[k * 128 + n]);
  WT2[n * 128 + k] = (ushort)f2bf(W2[k * 128 + n]);
  WT3[n * 128 + k] = (n < 40) ? (ushort)f2bf(W3[k * 40 + n]) : (ushort)0;
  if (k == 0) {
    float s1 = g1[n] * rsqrtf(v1[n] + BN_EPS);
    sc1[n] = s1; sh1[n] = be1[n] - m1[n] * s1;
    float s2 = g2[n] * rsqrtf(v2[n] + BN_EPS);
    sc2[n] = s2; sh2[n] = be2[n] - m2[n] * s2;
  } else if (k == 1 && n < 64) {
    b3pad[n] = (n < 40) ? b3[n] : 0.f;
  }
}

// ---------------- MFMA GEMM: C[nrows x NC](bf16) = A[nrows x 128] * W[128 x NC] --------
// WT: 128x128 n-major bf16 pre-transposed weight (zero-padded). F32A: A is fp32.

template <bool F32A>
__global__ __launch_bounds__(256) void k_gemm_bf16(const void* __restrict__ Ap,
                                                   const ushort* __restrict__ WT,
                                                   ushort* __restrict__ C,
                                                   int nrows, int NC) {
  __shared__ ushort As[128][80];
  __shared__ ushort Bs[128][80];
  const int tid  = threadIdx.x;
  const int lane = tid & 63;
  const int wid  = tid >> 6;
  const int wr   = wid >> 1, wc = wid & 1;
  const int row0 = blockIdx.x * 128;
  f32x4 acc[4][4] = {};

  const int mrow = lane & 15;
  const int kg   = (lane >> 4) * 8;

  for (int k0 = 0; k0 < 128; k0 += 64) {
    __syncthreads();
    for (int i = tid; i < 1024; i += 256) {        // A tile: 128 rows x 64 bf16
      int r = i >> 3, c = (i & 7) * 8;
      uint4 w = make_uint4(0, 0, 0, 0);
      if (row0 + r < nrows) {
        if (F32A) {
          const float* A = (const float*)Ap;
          float4 v0 = *(const float4*)(A + (size_t)(row0 + r) * 128 + k0 + c);
          float4 v1 = *(const float4*)(A + (size_t)(row0 + r) * 128 + k0 + c + 4);
          w.x = f2bf(v0.x) | (f2bf(v0.y) << 16);
          w.y = f2bf(v0.z) | (f2bf(v0.w) << 16);
          w.z = f2bf(v1.x) | (f2bf(v1.y) << 16);
          w.w = f2bf(v1.z) | (f2bf(v1.w) << 16);
        } else {
          const ushort* A = (const ushort*)Ap;
          w = *(const uint4*)(A + (size_t)(row0 + r) * 128 + k0 + c);
        }
      }
      *(uint4*)(&As[r][c]) = w;
    }
    for (int i = tid; i < 1024; i += 256) {        // B tile: 128 n-rows x 64 bf16 (k)
      int r = i >> 3, c = (i & 7) * 8;
      *(uint4*)(&Bs[r][c]) = *(const uint4*)(WT + r * 128 + k0 + c);
    }
    __syncthreads();

#pragma unroll
    for (int ks = 0; ks < 2; ks++) {
      bf16x8 a[4], b[4];
#pragma unroll
      for (int f = 0; f < 4; f++) {
        a[f] = *(const bf16x8*)(&As[wr * 64 + f * 16 + mrow][ks * 32 + kg]);
        b[f] = *(const bf16x8*)(&Bs[wc * 64 + f * 16 + mrow][ks * 32 + kg]);
      }
#pragma unroll
      for (int fm = 0; fm < 4; fm++)
#pragma unroll
        for (int fn = 0; fn < 4; fn++)
          acc[fm][fn] = __builtin_amdgcn_mfma_f32_16x16x32_bf16(a[fm], b[fn], acc[fm][fn], 0, 0, 0);
    }
  }

  // C/D layout: col = lane&15, row = (lane>>4)*4 + reg
  const int rl = (lane >> 4) * 4;
  const int cl = lane & 15;
#pragma unroll
  for (int fm = 0; fm < 4; fm++) {
#pragma unroll
    for (int r = 0; r < 4; r++) {
      int row = row0 + wr * 64 + fm * 16 + rl + r;
      if (row >= nrows) continue;
#pragma unroll
      for (int fn = 0; fn < 4; fn++) {
        int col = wc * 64 + fn * 16 + cl;
        if (col < NC) C[(size_t)row * NC + col] = (ushort)f2bf(acc[fm][fn][r]);
      }
    }
  }
}

// ---------------- Aggregation (D=128, bf16 in/out): out = relu(bn(A_hat*h + b)) --------
// Wave = 4 edge-groups x 16 lanes; lane gathers 8 channels (16B). Slot prefetch+shfl.

__global__ __launch_bounds__(256) void k_agg128b(const ushort* __restrict__ h,
                          const int* __restrict__ rowstart,
                          const int2* __restrict__ slot,
                          const float* __restrict__ dinv,
                          const float* __restrict__ bias,
                          const float* __restrict__ bnsc,
                          const float* __restrict__ bnsh,
                          ushort* __restrict__ out, int nnodes) {
  int node = blockIdx.x * 4 + threadIdx.y;
  if (node >= nnodes) return;
  int lane = threadIdx.x;
  int eg = lane >> 4, cl = lane & 15, c0 = cl * 8;
  int s = rowstart[node], e = rowstart[node + 1];
  int deg = e - s;
  int2 mys = make_int2(0, 0);
  if (lane < deg) mys = slot[s + lane];
  float a[8] = {0.f, 0.f, 0.f, 0.f, 0.f, 0.f, 0.f, 0.f};
  int nb = deg < 64 ? deg : 64;
  for (int i = eg; i < nb; i += 4) {
    int src = __shfl(mys.x, i);
    float nrm = __int_as_float(__shfl(mys.y, i));
    uint4 hv = *(const uint4*)(h + (size_t)src * 128 + c0);
    acc8(a, hv, nrm);
  }
  for (int i = s + 64 + eg; i < e; i += 4) {     // rare tail (deg > 64)
    int2 p = slot[i];
    uint4 hv = *(const uint4*)(h + (size_t)p.x * 128 + c0);
    acc8(a, hv, __int_as_float(p.y));
  }
#pragma unroll
  for (int j = 0; j < 8; j++) {
    a[j] += __shfl_xor(a[j], 16);
    a[j] += __shfl_xor(a[j], 32);
  }
  if (eg == 0) {
    uint4 hv = *(const uint4*)(h + (size_t)node * 128 + c0);
    acc8(a, hv, dinv[node]);
    float4 bb0 = *(const float4*)(bias + c0), bb1 = *(const float4*)(bias + c0 + 4);
    float4 sc0 = *(const float4*)(bnsc + c0), sc1 = *(const float4*)(bnsc + c0 + 4);
    float4 sh0 = *(const float4*)(bnsh + c0), sh1 = *(const float4*)(bnsh + c0 + 4);
    float o0 = fmaxf((a[0] + bb0.x) * sc0.x + sh0.x, 0.f);
    float o1 = fmaxf((a[1] + bb0.y) * sc0.y + sh0.y, 0.f);
    float o2 = fmaxf((a[2] + bb0.z) * sc0.z + sh0.z, 0.f);
    float o3 = fmaxf((a[3] + bb0.w) * sc0.w + sh0.w, 0.f);
    float o4 = fmaxf((a[4] + bb1.x) * sc1.x + sh1.x, 0.f);
    float o5 = fmaxf((a[5] + bb1.y) * sc1.y + sh1.y, 0.f);
    float o6 = fmaxf((a[6] + bb1.z) * sc1.z + sh1.z, 0.f);
    float o7 = fmaxf((a[7] + bb1.w) * sc1.w + sh1.w, 0.f);
    uint4 w;
    w.x = f2bf(o0) | (f2bf(o1) << 16);
    w.y = f2bf(o2) | (f2bf(o3) << 16);
    w.z = f2bf(o4) | (f2bf(o5) << 16);
    w.w = f2bf(o6) | (f2bf(o7) << 16);
    *(uint4*)(out + (size_t)node * 128 + c0) = w;
  }
}

// -------- Aggregation (64-padded layer-3, bf16 in) + log_softmax (fp32 out, 40 ch) -----

__global__ __launch_bounds__(256) void k_agg64_lsm(const ushort* __restrict__ h,
                            const int* __restrict__ rowstart,
                            const int2* __restrict__ slot,
                            const float* __restrict__ dinv,
                            const float* __restrict__ b3pad,
                            float* __restrict__ out, int nnodes) {
  int node = blockIdx.x * 4 + threadIdx.y;
  if (node >= nnodes) return;
  int lane = threadIdx.x;
  int eg = lane >> 4, cl = lane & 15, c0 = cl * 4;
  int s = rowstart[node], e = rowstart[node + 1];
  int deg = e - s;
  int2 mys = make_int2(0, 0);
  if (lane < deg) mys = slot[s + lane];
  float a[4] = {0.f, 0.f, 0.f, 0.f};
  int nb = deg < 64 ? deg : 64;
  for (int i = eg; i < nb; i += 4) {
    int src = __shfl(mys.x, i);
    float nrm = __int_as_float(__shfl(mys.y, i));
    uint2 hv = *(const uint2*)(h + (size_t)src * 64 + c0);
    acc4(a, hv, nrm);
  }
  for (int i = s + 64 + eg; i < e; i += 4) {
    int2 p = slot[i];
    uint2 hv = *(const uint2*)(h + (size_t)p.x * 64 + c0);
    acc4(a, hv, __int_as_float(p.y));
  }
#pragma unroll
  for (int j = 0; j < 4; j++) {
    a[j] += __shfl_xor(a[j], 16);
    a[j] += __shfl_xor(a[j], 32);
  }
  // self loop + bias (identical across edge groups)
  {
    uint2 hv = *(const uint2*)(h + (size_t)node * 64 + c0);
    float di = dinv[node];
    float4 bb = *(const float4*)(b3pad + c0);
    a[0] += __uint_as_float(hv.x << 16) * di + bb.x;
    a[1] += __uint_as_float(hv.x & 0xffff0000u) * di + bb.y;
    a[2] += __uint_as_float(hv.y << 16) * di + bb.z;
    a[3] += __uint_as_float(hv.y & 0xffff0000u) * di + bb.w;
  }
  bool valid = cl < 10;   // channels 4*cl..4*cl+3 < 40
  float m = valid ? fmaxf(fmaxf(a[0], a[1]), fmaxf(a[2], a[3])) : -INFINITY;
#pragma unroll
  for (int off = 1; off < 16; off <<= 1) m = fmaxf(m, __shfl_xor(m, off));
  float ss = valid ? (expf(a[0] - m) + expf(a[1] - m) + expf(a[2] - m) + expf(a[3] - m)) : 0.f;
#pragma unroll
  for (int off = 1; off < 16; off <<= 1) ss += __shfl_xor(ss, off);
  float lse = m + logf(ss);
  if (eg == 0 && valid) {
    *(float4*)(out + (size_t)node * 40 + c0) =
        make_float4(a[0] - lse, a[1] - lse, a[2] - lse, a[3] - lse);
  }
}

// ---------------- launch ----------------

extern "C" void kernel_launch(void* const* d_in, const int* in_sizes, int n_in,
                              void* d_out, int out_size, void* d_ws, size_t ws_size,
                              hipStream_t stream) {
  const float* x   = (const float*)d_in[0];
  const int*   ei  = (const int*)d_in[1];
  const float* W1  = (const float*)d_in[2];
  const float* b1  = (const float*)d_in[3];
  const float* W2  = (const float*)d_in[4];
  const float* b2  = (const float*)d_in[5];
  const float* W3  = (const float*)d_in[6];
  const float* b3  = (const float*)d_in[7];
  const float* g1  = (const float*)d_in[8];
  const float* be1 = (const float*)d_in[9];
  const float* m1  = (const float*)d_in[10];
  const float* v1  = (const float*)d_in[11];
  const float* g2  = (const float*)d_in[12];
  const float* be2 = (const float*)d_in[13];
  const float* m2  = (const float*)d_in[14];
  const float* v2  = (const float*)d_in[15];

  const int N   = in_sizes[0] / 128;
  const int E   = in_sizes[1] / 2;

  float* outp = (float*)d_out;

  char* ws = (char*)d_ws;
  size_t off = 0;
  auto alloc = [&](size_t bytes) -> char* {
    char* p = ws + off;
    off = (off + bytes + 255) & ~(size_t)255;
    return p;
  };
  int*    deg      = (int*)alloc((size_t)2 * N * 4);   // deg + cursor (one memset)
  int*    cursor   = deg + N;
  int*    rowstart = (int*)alloc((size_t)(N + 1) * 4);
  int*    chunksum = (int*)alloc(256 * 4);
  float*  dis      = (float*)alloc((size_t)N * 4);
  float*  dinv     = (float*)alloc((size_t)N * 4);
  int2*   slot     = (int2*)alloc((size_t)E * 8);
  float*  sc1      = (float*)alloc(128 * 4);
  float*  sh1      = (float*)alloc(128 * 4);
  float*  sc2      = (float*)alloc(128 * 4);
  float*  sh2      = (float*)alloc(128 * 4);
  float*  b3pad    = (float*)alloc(64 * 4);
  ushort* WT1      = (ushort*)alloc(128 * 128 * 2);
  ushort* WT2      = (ushort*)alloc(128 * 128 * 2);
  ushort* WT3      = (ushort*)alloc(128 * 128 * 2);
  ushort* bufA     = (ushort*)alloc((size_t)N * 128 * 2);
  ushort* bufB     = (ushort*)alloc((size_t)N * 128 * 2);
  ushort* bufC     = (ushort*)alloc((size_t)N * 64 * 2);
  (void)ws_size;

  const int T = 256;
  const int chunks = (N + 1023) / 1024;

  hipMemsetAsync(deg, 0, (size_t)2 * N * 4, stream);
  k_count<<<(E + T - 1) / T, T, 0, stream>>>(ei + E, deg, E);
  k_scan1<<<chunks, 1024, 0, stream>>>(deg, rowstart, chunksum, N);
  k_scan2<<<1, 64, 0, stream>>>(chunksum, chunks);
  k_scan3<<<(N + T - 1) / T, T, 0, stream>>>(rowstart, chunksum, deg, dis, dinv, N, E);
  k_fill<<<(E + T - 1) / T, T, 0, stream>>>(ei, rowstart, cursor, dis, slot, E);
  k_prep<<<128, 128, 0, stream>>>(W1, W2, W3, g1, be1, m1, v1, g2, be2, m2, v2, b3,
                                  WT1, WT2, WT3, sc1, sh1, sc2, sh2, b3pad);

  dim3 aggGrid((N + 3) / 4), aggBlk(64, 4);
  const int gBlocks = (N + 127) / 128;

  // Layer 1 (fp32 input converted in GEMM staging)
  k_gemm_bf16<true><<<gBlocks, 256, 0, stream>>>(x, WT1, bufB, N, 128);
  k_agg128b<<<aggGrid, aggBlk, 0, stream>>>(bufB, rowstart, slot, dinv, b1, sc1, sh1, bufA, N);

  // Layer 2
  k_gemm_bf16<false><<<gBlocks, 256, 0, stream>>>(bufA, WT2, bufB, N, 128);
  k_agg128b<<<aggGrid, aggBlk, 0, stream>>>(bufB, rowstart, slot, dinv, b2, sc2, sh2, bufA, N);

  // Layer 3 (64-padded) + log_softmax
  k_gemm_bf16<false><<<gBlocks, 256, 0, stream>>>(bufA, WT3, bufC, N, 64);
  k_agg64_lsm<<<aggGrid, aggBlk, 0, stream>>>(bufC, rowstart, slot, dinv, b3pad, outp, N);
}

// Round 4
// 211.537 us; speedup vs baseline: 2.1870x; 1.1119x over previous
//
#include <hip/hip_runtime.h>
#include <math.h>

#define BN_EPS 1e-5f

typedef __attribute__((ext_vector_type(8))) short bf16x8;
typedef __attribute__((ext_vector_type(4))) float f32x4;

__device__ inline unsigned f2bf(float f) {
  union { float f; unsigned u; } v; v.f = f;
  unsigned r = v.u + 0x7FFF + ((v.u >> 16) & 1);   // round-nearest-even
  return r >> 16;
}

__device__ inline void acc8(float* a, uint4 v, float nrm) {
  a[0] += __uint_as_float(v.x << 16) * nrm;
  a[1] += __uint_as_float(v.x & 0xffff0000u) * nrm;
  a[2] += __uint_as_float(v.y << 16) * nrm;
  a[3] += __uint_as_float(v.y & 0xffff0000u) * nrm;
  a[4] += __uint_as_float(v.z << 16) * nrm;
  a[5] += __uint_as_float(v.z & 0xffff0000u) * nrm;
  a[6] += __uint_as_float(v.w << 16) * nrm;
  a[7] += __uint_as_float(v.w & 0xffff0000u) * nrm;
}

__device__ inline void acc4(float* a, uint2 v, float nrm) {
  a[0] += __uint_as_float(v.x << 16) * nrm;
  a[1] += __uint_as_float(v.x & 0xffff0000u) * nrm;
  a[2] += __uint_as_float(v.y << 16) * nrm;
  a[3] += __uint_as_float(v.y & 0xffff0000u) * nrm;
}

// ---------------- zero ----------------

__global__ void k_zero(uint4* __restrict__ p, int n16) {
  int i = blockIdx.x * blockDim.x + threadIdx.x;
  if (i < n16) p[i] = make_uint4(0, 0, 0, 0);
}

// ---------------- CSR build ----------------
// count + within-node position in one atomic pass

__global__ void k_count(const int* __restrict__ dst, int* __restrict__ deg,
                        int* __restrict__ posw, int E) {
  int e = blockIdx.x * blockDim.x + threadIdx.x;
  if (e < E) posw[e] = atomicAdd(&deg[dst[e]], 1);
}

__global__ void k_scan1(const int* __restrict__ deg, int* __restrict__ rowstart,
                        int* __restrict__ chunksum, int n) {
  __shared__ int s[1024];
  int i = blockIdx.x * 1024 + threadIdx.x;
  int v = (i < n) ? deg[i] : 0;
  s[threadIdx.x] = v;
  __syncthreads();
  for (int off = 1; off < 1024; off <<= 1) {
    int t = (threadIdx.x >= off) ? s[threadIdx.x - off] : 0;
    __syncthreads();
    s[threadIdx.x] += t;
    __syncthreads();
  }
  if (i < n) rowstart[i] = s[threadIdx.x] - v;   // exclusive within chunk
  if (threadIdx.x == 1023) chunksum[blockIdx.x] = s[1023];
}

__global__ void k_scan2(int* __restrict__ chunksum, int nchunks) {
  if (threadIdx.x == 0 && blockIdx.x == 0) {
    int run = 0;
    for (int i = 0; i < nchunks; i++) { int v = chunksum[i]; chunksum[i] = run; run += v; }
  }
}

__global__ void k_scan3(int* __restrict__ rowstart, const int* __restrict__ chunksum,
                        const int* __restrict__ deg, float* __restrict__ dis,
                        float* __restrict__ dinv, int n, int E) {
  int i = blockIdx.x * blockDim.x + threadIdx.x;
  if (i < n) {
    rowstart[i] += chunksum[i >> 10];
    float fd = (float)(deg[i] + 1);   // +1 self loop
    dis[i]  = rsqrtf(fd);
    dinv[i] = 1.0f / fd;
  }
  if (i == 0) rowstart[n] = E;
}

// atomic-free scatter: pos = rowstart[d] + posw[e]
__global__ void k_fill(const int* __restrict__ ei, const int* __restrict__ rowstart,
                       const int* __restrict__ posw, const float* __restrict__ dis,
                       int2* __restrict__ slot, int E) {
  int e = blockIdx.x * blockDim.x + threadIdx.x;
  if (e >= E) return;
  int s = ei[e];        // row 0 = src
  int d = ei[E + e];    // row 1 = dst
  int2 p; p.x = s; p.y = __float_as_int(dis[s] * dis[d]);
  slot[rowstart[d] + posw[e]] = p;
}

// ------------- prep: BN fold + weight transpose/bf16 + b3 pad (one kernel) -------------

__global__ void k_prep(const float* __restrict__ W1, const float* __restrict__ W2,
                       const float* __restrict__ W3,
                       const float* __restrict__ g1, const float* __restrict__ be1,
                       const float* __restrict__ m1, const float* __restrict__ v1,
                       const float* __restrict__ g2, const float* __restrict__ be2,
                       const float* __restrict__ m2, const float* __restrict__ v2,
                       const float* __restrict__ b3,
                       ushort* __restrict__ WT1, ushort* __restrict__ WT2,
                       ushort* __restrict__ WT3,
                       float* __restrict__ sc1, float* __restrict__ sh1,
                       float* __restrict__ sc2, float* __restrict__ sh2,
                       float* __restrict__ b3pad) {
  int k = blockIdx.x;      // 128
  int n = threadIdx.x;     // 128
  WT1[n * 128 + k] = (ushort)f2bf(W1[k * 128 + n]);
  WT2[n * 128 + k] = (ushort)f2bf(W2[k * 128 + n]);
  WT3[n * 128 + k] = (n < 40) ? (ushort)f2bf(W3[k * 40 + n]) : (ushort)0;
  if (k == 0) {
    float s1 = g1[n] * rsqrtf(v1[n] + BN_EPS);
    sc1[n] = s1; sh1[n] = be1[n] - m1[n] * s1;
    float s2 = g2[n] * rsqrtf(v2[n] + BN_EPS);
    sc2[n] = s2; sh2[n] = be2[n] - m2[n] * s2;
  } else if (k == 1 && n < 64) {
    b3pad[n] = (n < 40) ? b3[n] : 0.f;
  }
}

// ---------------- MFMA GEMM: C[nrows x NC](bf16) = A[nrows x 128] * W[128 x NC] --------

template <bool F32A>
__global__ __launch_bounds__(256) void k_gemm_bf16(const void* __restrict__ Ap,
                                                   const ushort* __restrict__ WT,
                                                   ushort* __restrict__ C,
                                                   int nrows, int NC) {
  __shared__ ushort As[128][80];
  __shared__ ushort Bs[128][80];
  const int tid  = threadIdx.x;
  const int lane = tid & 63;
  const int wid  = tid >> 6;
  const int wr   = wid >> 1, wc = wid & 1;
  const int row0 = blockIdx.x * 128;
  f32x4 acc[4][4] = {};

  const int mrow = lane & 15;
  const int kg   = (lane >> 4) * 8;

  for (int k0 = 0; k0 < 128; k0 += 64) {
    __syncthreads();
    for (int i = tid; i < 1024; i += 256) {        // A tile: 128 rows x 64 bf16
      int r = i >> 3, c = (i & 7) * 8;
      uint4 w = make_uint4(0, 0, 0, 0);
      if (row0 + r < nrows) {
        if (F32A) {
          const float* A = (const float*)Ap;
          float4 v0 = *(const float4*)(A + (size_t)(row0 + r) * 128 + k0 + c);
          float4 v1 = *(const float4*)(A + (size_t)(row0 + r) * 128 + k0 + c + 4);
          w.x = f2bf(v0.x) | (f2bf(v0.y) << 16);
          w.y = f2bf(v0.z) | (f2bf(v0.w) << 16);
          w.z = f2bf(v1.x) | (f2bf(v1.y) << 16);
          w.w = f2bf(v1.z) | (f2bf(v1.w) << 16);
        } else {
          const ushort* A = (const ushort*)Ap;
          w = *(const uint4*)(A + (size_t)(row0 + r) * 128 + k0 + c);
        }
      }
      *(uint4*)(&As[r][c]) = w;
    }
    for (int i = tid; i < 1024; i += 256) {        // B tile: 128 n-rows x 64 bf16 (k)
      int r = i >> 3, c = (i & 7) * 8;
      *(uint4*)(&Bs[r][c]) = *(const uint4*)(WT + r * 128 + k0 + c);
    }
    __syncthreads();

#pragma unroll
    for (int ks = 0; ks < 2; ks++) {
      bf16x8 a[4], b[4];
#pragma unroll
      for (int f = 0; f < 4; f++) {
        a[f] = *(const bf16x8*)(&As[wr * 64 + f * 16 + mrow][ks * 32 + kg]);
        b[f] = *(const bf16x8*)(&Bs[wc * 64 + f * 16 + mrow][ks * 32 + kg]);
      }
#pragma unroll
      for (int fm = 0; fm < 4; fm++)
#pragma unroll
        for (int fn = 0; fn < 4; fn++)
          acc[fm][fn] = __builtin_amdgcn_mfma_f32_16x16x32_bf16(a[fm], b[fn], acc[fm][fn], 0, 0, 0);
    }
  }

  // C/D layout: col = lane&15, row = (lane>>4)*4 + reg
  const int rl = (lane >> 4) * 4;
  const int cl = lane & 15;
#pragma unroll
  for (int fm = 0; fm < 4; fm++) {
#pragma unroll
    for (int r = 0; r < 4; r++) {
      int row = row0 + wr * 64 + fm * 16 + rl + r;
      if (row >= nrows) continue;
#pragma unroll
      for (int fn = 0; fn < 4; fn++) {
        int col = wc * 64 + fn * 16 + cl;
        if (col < NC) C[(size_t)row * NC + col] = (ushort)f2bf(acc[fm][fn][r]);
      }
    }
  }
}

// ---------------- Aggregation (D=128, bf16 in/out): out = relu(bn(A_hat*h + b)) --------
// Wave = 4 edge-groups x 16 lanes; lane gathers 8 channels (16B). Slot prefetch+shfl.

__global__ __launch_bounds__(256) void k_agg128b(const ushort* __restrict__ h,
                          const int* __restrict__ rowstart,
                          const int2* __restrict__ slot,
                          const float* __restrict__ dinv,
                          const float* __restrict__ bias,
                          const float* __restrict__ bnsc,
                          const float* __restrict__ bnsh,
                          ushort* __restrict__ out, int nnodes) {
  int node = blockIdx.x * 4 + threadIdx.y;
  if (node >= nnodes) return;
  int lane = threadIdx.x;
  int eg = lane >> 4, cl = lane & 15, c0 = cl * 8;
  int s = rowstart[node], e = rowstart[node + 1];
  int deg = e - s;
  int2 mys = make_int2(0, 0);
  if (lane < deg) mys = slot[s + lane];
  float a[8] = {0.f, 0.f, 0.f, 0.f, 0.f, 0.f, 0.f, 0.f};
  int nb = deg < 64 ? deg : 64;
  for (int i = eg; i < nb; i += 4) {
    int src = __shfl(mys.x, i);
    float nrm = __int_as_float(__shfl(mys.y, i));
    uint4 hv = *(const uint4*)(h + (size_t)src * 128 + c0);
    acc8(a, hv, nrm);
  }
  for (int i = s + 64 + eg; i < e; i += 4) {     // rare tail (deg > 64)
    int2 p = slot[i];
    uint4 hv = *(const uint4*)(h + (size_t)p.x * 128 + c0);
    acc8(a, hv, __int_as_float(p.y));
  }
#pragma unroll
  for (int j = 0; j < 8; j++) {
    a[j] += __shfl_xor(a[j], 16);
    a[j] += __shfl_xor(a[j], 32);
  }
  if (eg == 0) {
    uint4 hv = *(const uint4*)(h + (size_t)node * 128 + c0);
    acc8(a, hv, dinv[node]);
    float4 bb0 = *(const float4*)(bias + c0), bb1 = *(const float4*)(bias + c0 + 4);
    float4 sc0 = *(const float4*)(bnsc + c0), sc1 = *(const float4*)(bnsc + c0 + 4);
    float4 sh0 = *(const float4*)(bnsh + c0), sh1 = *(const float4*)(bnsh + c0 + 4);
    float o0 = fmaxf((a[0] + bb0.x) * sc0.x + sh0.x, 0.f);
    float o1 = fmaxf((a[1] + bb0.y) * sc0.y + sh0.y, 0.f);
    float o2 = fmaxf((a[2] + bb0.z) * sc0.z + sh0.z, 0.f);
    float o3 = fmaxf((a[3] + bb0.w) * sc0.w + sh0.w, 0.f);
    float o4 = fmaxf((a[4] + bb1.x) * sc1.x + sh1.x, 0.f);
    float o5 = fmaxf((a[5] + bb1.y) * sc1.y + sh1.y, 0.f);
    float o6 = fmaxf((a[6] + bb1.z) * sc1.z + sh1.z, 0.f);
    float o7 = fmaxf((a[7] + bb1.w) * sc1.w + sh1.w, 0.f);
    uint4 w;
    w.x = f2bf(o0) | (f2bf(o1) << 16);
    w.y = f2bf(o2) | (f2bf(o3) << 16);
    w.z = f2bf(o4) | (f2bf(o5) << 16);
    w.w = f2bf(o6) | (f2bf(o7) << 16);
    *(uint4*)(out + (size_t)node * 128 + c0) = w;
  }
}

// -------- Aggregation (64-padded layer-3, bf16 in) + log_softmax (fp32 out, 40 ch) -----

__global__ __launch_bounds__(256) void k_agg64_lsm(const ushort* __restrict__ h,
                            const int* __restrict__ rowstart,
                            const int2* __restrict__ slot,
                            const float* __restrict__ dinv,
                            const float* __restrict__ b3pad,
                            float* __restrict__ out, int nnodes) {
  int node = blockIdx.x * 4 + threadIdx.y;
  if (node >= nnodes) return;
  int lane = threadIdx.x;
  int eg = lane >> 4, cl = lane & 15, c0 = cl * 4;
  int s = rowstart[node], e = rowstart[node + 1];
  int deg = e - s;
  int2 mys = make_int2(0, 0);
  if (lane < deg) mys = slot[s + lane];
  float a[4] = {0.f, 0.f, 0.f, 0.f};
  int nb = deg < 64 ? deg : 64;
  for (int i = eg; i < nb; i += 4) {
    int src = __shfl(mys.x, i);
    float nrm = __int_as_float(__shfl(mys.y, i));
    uint2 hv = *(const uint2*)(h + (size_t)src * 64 + c0);
    acc4(a, hv, nrm);
  }
  for (int i = s + 64 + eg; i < e; i += 4) {
    int2 p = slot[i];
    uint2 hv = *(const uint2*)(h + (size_t)p.x * 64 + c0);
    acc4(a, hv, __int_as_float(p.y));
  }
#pragma unroll
  for (int j = 0; j < 4; j++) {
    a[j] += __shfl_xor(a[j], 16);
    a[j] += __shfl_xor(a[j], 32);
  }
  // self loop + bias (identical across edge groups)
  {
    uint2 hv = *(const uint2*)(h + (size_t)node * 64 + c0);
    float di = dinv[node];
    float4 bb = *(const float4*)(b3pad + c0);
    a[0] += __uint_as_float(hv.x << 16) * di + bb.x;
    a[1] += __uint_as_float(hv.x & 0xffff0000u) * di + bb.y;
    a[2] += __uint_as_float(hv.y << 16) * di + bb.z;
    a[3] += __uint_as_float(hv.y & 0xffff0000u) * di + bb.w;
  }
  bool valid = cl < 10;   // channels 4*cl..4*cl+3 < 40
  float m = valid ? fmaxf(fmaxf(a[0], a[1]), fmaxf(a[2], a[3])) : -INFINITY;
#pragma unroll
  for (int off = 1; off < 16; off <<= 1) m = fmaxf(m, __shfl_xor(m, off));
  float ss = valid ? (expf(a[0] - m) + expf(a[1] - m) + expf(a[2] - m) + expf(a[3] - m)) : 0.f;
#pragma unroll
  for (int off = 1; off < 16; off <<= 1) ss += __shfl_xor(ss, off);
  float lse = m + logf(ss);
  if (eg == 0 && valid) {
    *(float4*)(out + (size_t)node * 40 + c0) =
        make_float4(a[0] - lse, a[1] - lse, a[2] - lse, a[3] - lse);
  }
}

// ---------------- launch ----------------

extern "C" void kernel_launch(void* const* d_in, const int* in_sizes, int n_in,
                              void* d_out, int out_size, void* d_ws, size_t ws_size,
                              hipStream_t stream) {
  const float* x   = (const float*)d_in[0];
  const int*   ei  = (const int*)d_in[1];
  const float* W1  = (const float*)d_in[2];
  const float* b1  = (const float*)d_in[3];
  const float* W2  = (const float*)d_in[4];
  const float* b2  = (const float*)d_in[5];
  const float* W3  = (const float*)d_in[6];
  const float* b3  = (const float*)d_in[7];
  const float* g1  = (const float*)d_in[8];
  const float* be1 = (const float*)d_in[9];
  const float* m1  = (const float*)d_in[10];
  const float* v1  = (const float*)d_in[11];
  const float* g2  = (const float*)d_in[12];
  const float* be2 = (const float*)d_in[13];
  const float* m2  = (const float*)d_in[14];
  const float* v2  = (const float*)d_in[15];

  const int N   = in_sizes[0] / 128;
  const int E   = in_sizes[1] / 2;

  float* outp = (float*)d_out;

  char* ws = (char*)d_ws;
  size_t off = 0;
  auto alloc = [&](size_t bytes) -> char* {
    char* p = ws + off;
    off = (off + bytes + 255) & ~(size_t)255;
    return p;
  };
  int*    deg      = (int*)alloc((size_t)N * 4);
  int*    posw     = (int*)alloc((size_t)E * 4);
  int*    rowstart = (int*)alloc((size_t)(N + 1) * 4);
  int*    chunksum = (int*)alloc(256 * 4);
  float*  dis      = (float*)alloc((size_t)N * 4);
  float*  dinv     = (float*)alloc((size_t)N * 4);
  int2*   slot     = (int2*)alloc((size_t)E * 8);
  float*  sc1      = (float*)alloc(128 * 4);
  float*  sh1      = (float*)alloc(128 * 4);
  float*  sc2      = (float*)alloc(128 * 4);
  float*  sh2      = (float*)alloc(128 * 4);
  float*  b3pad    = (float*)alloc(64 * 4);
  ushort* WT1      = (ushort*)alloc(128 * 128 * 2);
  ushort* WT2      = (ushort*)alloc(128 * 128 * 2);
  ushort* WT3      = (ushort*)alloc(128 * 128 * 2);
  ushort* bufA     = (ushort*)alloc((size_t)N * 128 * 2);
  ushort* bufB     = (ushort*)alloc((size_t)N * 128 * 2);
  ushort* bufC     = (ushort*)alloc((size_t)N * 64 * 2);
  (void)ws_size;

  const int T = 256;
  const int chunks = (N + 1023) / 1024;

  k_zero<<<(N / 4 + T - 1) / T, T, 0, stream>>>((uint4*)deg, (N + 3) / 4);
  k_count<<<(E + T - 1) / T, T, 0, stream>>>(ei + E, deg, posw, E);
  k_scan1<<<chunks, 1024, 0, stream>>>(deg, rowstart, chunksum, N);
  k_scan2<<<1, 64, 0, stream>>>(chunksum, chunks);
  k_scan3<<<(N + T - 1) / T, T, 0, stream>>>(rowstart, chunksum, deg, dis, dinv, N, E);
  k_fill<<<(E + T - 1) / T, T, 0, stream>>>(ei, rowstart, posw, dis, slot, E);
  k_prep<<<128, 128, 0, stream>>>(W1, W2, W3, g1, be1, m1, v1, g2, be2, m2, v2, b3,
                                  WT1, WT2, WT3, sc1, sh1, sc2, sh2, b3pad);

  dim3 aggGrid((N + 3) / 4), aggBlk(64, 4);
  const int gBlocks = (N + 127) / 128;

  // Layer 1 (fp32 input converted in GEMM staging)
  k_gemm_bf16<true><<<gBlocks, 256, 0, stream>>>(x, WT1, bufB, N, 128);
  k_agg128b<<<aggGrid, aggBlk, 0, stream>>>(bufB, rowstart, slot, dinv, b1, sc1, sh1, bufA, N);

  // Layer 2
  k_gemm_bf16<false><<<gBlocks, 256, 0, stream>>>(bufA, WT2, bufB, N, 128);
  k_agg128b<<<aggGrid, aggBlk, 0, stream>>>(bufB, rowstart, slot, dinv, b2, sc2, sh2, bufA, N);

  // Layer 3 (64-padded) + log_softmax
  k_gemm_bf16<false><<<gBlocks, 256, 0, stream>>>(bufA, WT3, bufC, N, 64);
  k_agg64_lsm<<<aggGrid, aggBlk, 0, stream>>>(bufC, rowstart, slot, dinv, b3pad, outp, N);
}